// Round 15
// baseline (126.878 us; speedup 1.0000x reference)
//
#include <hip/hip_runtime.h>
#include <math.h>

#define N_ROWS 4096
#define DIM    128
#define A_LAB  512
#define INV_TAU 14.285714285714286f
#define C_EXP   20.609929155556620f   // INV_TAU * log2(e)

typedef __attribute__((ext_vector_type(8))) short short8;   // 8 bf16 (4 VGPRs)
typedef __attribute__((ext_vector_type(4))) float f32x4;    // MFMA C/D frag (16x16)
typedef __attribute__((ext_vector_type(4))) int i32x4;      // i8 MFMA A/B frag
typedef __attribute__((ext_vector_type(16))) int i32x16;    // i8 MFMA C/D frag (32x32)

// ---------------- workspace layout (bytes) ----------------
// zbf   u16 [8192*128]   @ 0          (2,097,152)  FRAG-MAJOR (see k_norm_pack)
// labs8 i8  [4096*512]   @ 2,097,152  (2,097,152)  FRAG-MAJOR (see k_norm_pack)
// s     i32 [4096]       @ 4,194,304  (16,384)
// part  f32 [3*4096]     @ 4,210,688  (49,152)     atomically accumulated

__device__ __forceinline__ unsigned short f2bf(float f) {
  unsigned int u = __builtin_bit_cast(unsigned int, f);
  u += 0x7fffu + ((u >> 16) & 1u);            // round-to-nearest-even
  return (unsigned short)(u >> 16);
}

// ------------ kernel 1: L2-normalize (-> bf16, frag-major) + labels -> i8 frag-major ------------
__global__ __launch_bounds__(256) void k_norm_pack(
    const float* __restrict__ z1, const float* __restrict__ z2,
    const int* __restrict__ labels,
    unsigned int* __restrict__ zbf, uint2* __restrict__ labs8,
    int* __restrict__ s, float* __restrict__ part, float* __restrict__ out)
{
  {
    const int idx = blockIdx.x * 256 + threadIdx.x;
    if (idx < 3 * 4096) part[idx] = 0.0f;
    if (idx == 0) out[0] = 0.0f;
  }
  const int wave = threadIdx.x >> 6, lane = threadIdx.x & 63;
  const int r = blockIdx.x * 4 + wave;         // 0..8191
  const float* src = (r < N_ROWS) ? (z1 + (size_t)r * DIM)
                                  : (z2 + (size_t)(r - N_ROWS) * DIM);
  float2 x = ((const float2*)src)[lane];
  float ss = x.x * x.x + x.y * x.y;
  #pragma unroll
  for (int off = 32; off > 0; off >>= 1) ss += __shfl_xor(ss, off);
  const float inv = 1.0f / fmaxf(sqrtf(ss), 1e-12f);
  const unsigned int lo = f2bf(x.x * inv);
  const unsigned int hi = f2bf(x.y * inv);
  {
    const int u = lane >> 2, p = lane & 3;
    const int kf = u >> 2, quad = u & 3;
    const int g = r >> 4;
    zbf[(size_t)(((g * 4 + kf) * 64) + ((r & 15) + (quad << 4))) * 4 + p] = (hi << 16) | lo;
  }

  if (r < N_ROWS) {
    const int4* lp = (const int4*)(labels + (size_t)r * A_LAB);
    const int4 a = lp[2 * lane], b = lp[2 * lane + 1];
    const unsigned int w0 = (unsigned int)(a.x != 0)       | ((unsigned int)(a.y != 0) << 8)
                          | ((unsigned int)(a.z != 0) << 16) | ((unsigned int)(a.w != 0) << 24);
    const unsigned int w1 = (unsigned int)(b.x != 0)       | ((unsigned int)(b.y != 0) << 8)
                          | ((unsigned int)(b.z != 0) << 16) | ((unsigned int)(b.w != 0) << 24);
    uint2 v; v.x = w0; v.y = w1;
    const int ul = lane >> 1, hp = lane & 1;
    const int ks = ul >> 1, h = ul & 1;
    const int g = r >> 5;
    labs8[(size_t)(((g * 16 + ks) * 64) + ((r & 31) + (h << 5))) * 2 + hp] = v;
    int cnt = __popc(w0) + __popc(w1);
    #pragma unroll
    for (int off = 32; off > 0; off >>= 1) cnt += __shfl_xor(cnt, off);
    if (lane == 0) s[r] = cnt;
  }
}

// ------------ kernel 2: FUSED triangular jaccard + sim + masked-softmax ------------
// Grid = 528 blocks, (bi<=bj). Off-diag block computes J once, SL=z1[bi]x z1[bj]^T
// once (harvested for BOTH bi-anchor row sums and bj-anchor column sums: pm is
// symmetric so the same bit serves both directions), SR (anchors bi, cols z2[bj])
// and SR2 (anchors bj, cols z2[bi], mask = pmL transposed via one LDS dword/nt).
// Diag blocks run the R14-verified diag path verbatim. Work = 0.69x of R14.
__global__ __launch_bounds__(512, 2) void k_fused(
    const unsigned char* __restrict__ labs8, const int* __restrict__ s,
    const unsigned short* __restrict__ zbf, float* __restrict__ part)
{
  __shared__ unsigned int pmL[128 * 4];       // pos-bits: [bi-local row][bj col word]
  const int tid = threadIdx.x;
  int t = blockIdx.x, bi = 0;                 // triangular decode: bi <= bj
  while (t >= 32 - bi) { t -= 32 - bi; ++bi; }
  const int bj = bi + t;
  const int ibase = bi * 128, jbase = bj * 128;
  const int wave = tid >> 6, lane = tid & 63;
  const bool diag = (bi == bj);
  const char* gl = (const char*)labs8;
  const char* gz = (const char*)zbf;

  // ---------------- phase J: jaccard (R14 verbatim) ----------------
  const int jwr = (wave >> 2) * 64;           // rows: waves 0-3 -> 0, 4-7 -> 64
  const int jwc = (wave & 3) * 32;            // cols: 32-wide slice per wave
  const int col32 = lane & 31, h = lane >> 5;

  const int s3i = 3 * s[ibase + jwr + lane];
  const int s3j = 3 * s[jbase + jwc + col32];

  i32x16 jacc[2];
  #pragma unroll
  for (int rt = 0; rt < 2; ++rt)
    #pragma unroll
    for (int e = 0; e < 16; ++e) jacc[rt][e] = 0;

  const int gI = (ibase + jwr) >> 5;
  const int gJ = (jbase + jwc) >> 5;
  #pragma unroll
  for (int batch = 0; batch < 2; ++batch) {
    i32x4 av[8][2], bv[8];
    #pragma unroll
    for (int k = 0; k < 8; ++k) {
      const int ks = batch * 8 + k;
      av[k][0] = *(const i32x4*)(gl + (size_t)((gI * 16 + ks) * 64 + lane) * 16);
      av[k][1] = *(const i32x4*)(gl + (size_t)(((gI + 1) * 16 + ks) * 64 + lane) * 16);
      bv[k]    = *(const i32x4*)(gl + (size_t)((gJ * 16 + ks) * 64 + lane) * 16);
    }
    #pragma unroll
    for (int k = 0; k < 8; ++k) {
      jacc[0] = __builtin_amdgcn_mfma_i32_32x32x32_i8(av[k][0], bv[k], jacc[0], 0, 0, 0);
      jacc[1] = __builtin_amdgcn_mfma_i32_32x32x32_i8(av[k][1], bv[k], jacc[1], 0, 0, 0);
    }
  }

  const int wl = wave & 3;
  #pragma unroll
  for (int rt = 0; rt < 2; ++rt)
    #pragma unroll
    for (int reg = 0; reg < 16; ++reg) {
      const int r0 = (reg & 3) + 8 * (reg >> 2);
      const int si = __shfl(s3i, rt * 32 + r0 + 4 * h);
      const bool pred = 13 * jacc[rt][reg] >= si + s3j;
      const unsigned long long bal = __ballot(pred);
      const int lr = jwr + rt * 32 + r0;
      if (lane == 0)      pmL[lr * 4 + wl]       = (unsigned int)bal;
      else if (lane == 1) pmL[(lr + 4) * 4 + wl] = (unsigned int)(bal >> 32);
    }

  // sim A-fragments for bi anchors (pre-barrier)
  const int col = lane & 15, quad = lane >> 4;
  const int srow = wave * 16;
  const int gA = (ibase + srow) >> 4;
  short8 afr[4];
  #pragma unroll
  for (int kf = 0; kf < 4; ++kf)
    afr[kf] = *(const short8*)(gz + (size_t)((gA * 4 + kf) * 64 + lane) * 16);

  __syncthreads();   // pmL visible to all waves

  uint4 pw[4];
  #pragma unroll
  for (int reg = 0; reg < 4; ++reg)
    pw[reg] = *(const uint4*)&pmL[(srow + quad * 4 + reg) * 4];

  if (diag) {
    // ---------------- R14 diag path verbatim ----------------
    float lacc[4], Sacc[4], Pcnt[4];
    #pragma unroll
    for (int reg = 0; reg < 4; ++reg) { lacc[reg] = 0; Sacc[reg] = 0; Pcnt[reg] = 0; }

    #pragma unroll
    for (int half = 0; half < 2; ++half) {
      const int gB = ((half ? N_ROWS : 0) + jbase) >> 4;
      f32x4 acc[8];
      #pragma unroll
      for (int nt = 0; nt < 8; ++nt) acc[nt] = (f32x4){0, 0, 0, 0};
      #pragma unroll
      for (int batch = 0; batch < 2; ++batch) {
        short8 bv[4][4];
        #pragma unroll
        for (int q = 0; q < 4; ++q) {
          const int nt = batch * 4 + q;
          #pragma unroll
          for (int kf = 0; kf < 4; ++kf)
            bv[q][kf] = *(const short8*)(gz + (size_t)(((gB + nt) * 4 + kf) * 64 + lane) * 16);
        }
        #pragma unroll
        for (int q = 0; q < 4; ++q) {
          const int nt = batch * 4 + q;
          #pragma unroll
          for (int kf = 0; kf < 4; ++kf)
            acc[nt] = __builtin_amdgcn_mfma_f32_16x16x32_bf16(afr[kf], bv[q][kf], acc[nt], 0, 0, 0);
        }
      }
      const bool left = (half == 0);
      #pragma unroll
      for (int nt = 0; nt < 8; ++nt) {
        const int joff = nt * 16 + col;
        const int jc = jbase + joff;
        const int bitpos = joff & 31;
        #pragma unroll
        for (int reg = 0; reg < 4; ++reg) {
          const int i = ibase + srow + quad * 4 + reg;
          const unsigned int w = ((const unsigned int*)&pw[reg])[nt >> 1];
          const float d = acc[nt][reg];
          const bool bit = (w >> bitpos) & 1;
          const bool self = left && (jc == i);
          const bool pos = left ? (bit && !self) : (bit || (jc == i));
          const float e = exp2f(fmaf(d, C_EXP, -C_EXP));
          if (!self) lacc[reg] += e;
          if (pos) { Sacc[reg] += d; Pcnt[reg] += 1.0f; }
        }
      }
    }
    #pragma unroll
    for (int reg = 0; reg < 4; ++reg) {
      float l = lacc[reg], S = Sacc[reg], P = Pcnt[reg];
      #pragma unroll
      for (int m = 1; m < 16; m <<= 1) {
        l += __shfl_xor(l, m);
        S += __shfl_xor(S, m);
        P += __shfl_xor(P, m);
      }
      if (col == 0) {
        const int i = ibase + srow + quad * 4 + reg;
        atomicAdd(&part[i], l);
        atomicAdd(&part[4096 + i], S);
        atomicAdd(&part[8192 + i], P);
      }
    }
  } else {
    // ---------------- off-diag: SL (dual harvest) + SR + SR2 ----------------
    float lacc[4], Sacc[4];
    #pragma unroll
    for (int reg = 0; reg < 4; ++reg) { lacc[reg] = 0; Sacc[reg] = 0; }

    // ---- SL: cols = z1[bj]; harvest rows (bi anchors) AND cols (bj anchors) ----
    {
      const int gB = jbase >> 4;
      f32x4 acc[8];
      #pragma unroll
      for (int nt = 0; nt < 8; ++nt) acc[nt] = (f32x4){0, 0, 0, 0};
      #pragma unroll
      for (int batch = 0; batch < 2; ++batch) {
        short8 bv[4][4];
        #pragma unroll
        for (int q = 0; q < 4; ++q) {
          const int nt = batch * 4 + q;
          #pragma unroll
          for (int kf = 0; kf < 4; ++kf)
            bv[q][kf] = *(const short8*)(gz + (size_t)(((gB + nt) * 4 + kf) * 64 + lane) * 16);
        }
        #pragma unroll
        for (int q = 0; q < 4; ++q) {
          const int nt = batch * 4 + q;
          #pragma unroll
          for (int kf = 0; kf < 4; ++kf)
            acc[nt] = __builtin_amdgcn_mfma_f32_16x16x32_bf16(afr[kf], bv[q][kf], acc[nt], 0, 0, 0);
        }
      }
      float lc[8], Sc[8], Pc[8];
      #pragma unroll
      for (int nt = 0; nt < 8; ++nt) { lc[nt] = 0; Sc[nt] = 0; Pc[nt] = 0; }
      #pragma unroll
      for (int nt = 0; nt < 8; ++nt) {
        const int bitpos = (nt & 1) * 16 + col;
        #pragma unroll
        for (int reg = 0; reg < 4; ++reg) {
          const unsigned int w = ((const unsigned int*)&pw[reg])[nt >> 1];
          const float d = acc[nt][reg];
          const bool bit = (w >> bitpos) & 1;
          const float e = exp2f(fmaf(d, C_EXP, -C_EXP));
          lacc[reg] += e; lc[nt] += e;
          if (bit) { Sacc[reg] += d; Sc[nt] += d; Pc[nt] += 1.0f; }
        }
      }
      // column scatter: reduce over the 4 quads; quad==0 lanes own col=lane
      #pragma unroll
      for (int nt = 0; nt < 8; ++nt) {
        float l = lc[nt], S = Sc[nt], P = Pc[nt];
        l += __shfl_xor(l, 16); l += __shfl_xor(l, 32);
        S += __shfl_xor(S, 16); S += __shfl_xor(S, 32);
        P += __shfl_xor(P, 16); P += __shfl_xor(P, 32);
        if (quad == 0) {
          const int j = jbase + nt * 16 + col;
          atomicAdd(&part[j], l);
          atomicAdd(&part[4096 + j], S);
          atomicAdd(&part[8192 + j], 2.0f * P);   // left(sym) + right(SR2) share count
        }
      }
    }

    // ---- SR: cols = z2[bj]; rows (bi anchors), slim ----
    {
      const int gB = (N_ROWS + jbase) >> 4;
      f32x4 acc[8];
      #pragma unroll
      for (int nt = 0; nt < 8; ++nt) acc[nt] = (f32x4){0, 0, 0, 0};
      #pragma unroll
      for (int batch = 0; batch < 2; ++batch) {
        short8 bv[4][4];
        #pragma unroll
        for (int q = 0; q < 4; ++q) {
          const int nt = batch * 4 + q;
          #pragma unroll
          for (int kf = 0; kf < 4; ++kf)
            bv[q][kf] = *(const short8*)(gz + (size_t)(((gB + nt) * 4 + kf) * 64 + lane) * 16);
        }
        #pragma unroll
        for (int q = 0; q < 4; ++q) {
          const int nt = batch * 4 + q;
          #pragma unroll
          for (int kf = 0; kf < 4; ++kf)
            acc[nt] = __builtin_amdgcn_mfma_f32_16x16x32_bf16(afr[kf], bv[q][kf], acc[nt], 0, 0, 0);
        }
      }
      #pragma unroll
      for (int nt = 0; nt < 8; ++nt) {
        const int bitpos = (nt & 1) * 16 + col;
        #pragma unroll
        for (int reg = 0; reg < 4; ++reg) {
          const unsigned int w = ((const unsigned int*)&pw[reg])[nt >> 1];
          const float d = acc[nt][reg];
          lacc[reg] += exp2f(fmaf(d, C_EXP, -C_EXP));
          if ((w >> bitpos) & 1) Sacc[reg] += d;
        }
      }
      // row scatter for bi anchors
      #pragma unroll
      for (int reg = 0; reg < 4; ++reg) {
        float l = lacc[reg], S = Sacc[reg];
        #pragma unroll
        for (int m = 1; m < 16; m <<= 1) { l += __shfl_xor(l, m); S += __shfl_xor(S, m); }
        if (col == 0) {
          const int i = ibase + srow + quad * 4 + reg;
          const uint4 w = pw[reg];
          const float P = 2.0f * (float)(__popc(w.x) + __popc(w.y) + __popc(w.z) + __popc(w.w));
          atomicAdd(&part[i], l);
          atomicAdd(&part[4096 + i], S);
          atomicAdd(&part[8192 + i], P);
        }
      }
    }

    // ---- SR2: anchors = bj rows, cols = z2[bi]; mask = pmL transposed ----
    {
      const int gA2 = (jbase + srow) >> 4;
      short8 afr2[4];
      #pragma unroll
      for (int kf = 0; kf < 4; ++kf)
        afr2[kf] = *(const short8*)(gz + (size_t)((gA2 * 4 + kf) * 64 + lane) * 16);
      const int gB2 = (N_ROWS + ibase) >> 4;
      f32x4 acc[8];
      #pragma unroll
      for (int nt = 0; nt < 8; ++nt) acc[nt] = (f32x4){0, 0, 0, 0};
      #pragma unroll
      for (int batch = 0; batch < 2; ++batch) {
        short8 bv[4][4];
        #pragma unroll
        for (int q = 0; q < 4; ++q) {
          const int nt = batch * 4 + q;
          #pragma unroll
          for (int kf = 0; kf < 4; ++kf)
            bv[q][kf] = *(const short8*)(gz + (size_t)(((gB2 + nt) * 4 + kf) * 64 + lane) * 16);
        }
        #pragma unroll
        for (int q = 0; q < 4; ++q) {
          const int nt = batch * 4 + q;
          #pragma unroll
          for (int kf = 0; kf < 4; ++kf)
            acc[nt] = __builtin_amdgcn_mfma_f32_16x16x32_bf16(afr2[kf], bv[q][kf], acc[nt], 0, 0, 0);
        }
      }
      float l2[4], S2[4];
      #pragma unroll
      for (int reg = 0; reg < 4; ++reg) { l2[reg] = 0; S2[reg] = 0; }
      const int bp0 = (wave & 1) * 16 + quad * 4;   // bit base for this lane's rows
      #pragma unroll
      for (int nt = 0; nt < 8; ++nt) {
        // transposed mask: row (bi-local) = nt*16+col, word = wave>>1
        const unsigned int mw = pmL[(nt * 16 + col) * 4 + (wave >> 1)];
        #pragma unroll
        for (int reg = 0; reg < 4; ++reg) {
          const float d = acc[nt][reg];
          l2[reg] += exp2f(fmaf(d, C_EXP, -C_EXP));
          if ((mw >> (bp0 + reg)) & 1) S2[reg] += d;
        }
      }
      #pragma unroll
      for (int reg = 0; reg < 4; ++reg) {
        float l = l2[reg], S = S2[reg];
        #pragma unroll
        for (int m = 1; m < 16; m <<= 1) { l += __shfl_xor(l, m); S += __shfl_xor(S, m); }
        if (col == 0) {
          const int i = jbase + srow + quad * 4 + reg;
          atomicAdd(&part[i], l);
          atomicAdd(&part[4096 + i], S);
        }
      }
    }
  }
}

// ---------------- kernel 3: per-anchor loss + atomic final reduce ----------------
__global__ __launch_bounds__(128) void k_loss(
    const float* __restrict__ part, float* __restrict__ out)
{
  const int a = blockIdx.x * 128 + threadIdx.x;   // 0..4095
  const float l = part[a];
  const float S = part[4096 + a];
  const float P = part[8192 + a];
  const float np = fmaxf(P, 1.0f);
  float v = INV_TAU + logf(l + 1e-8f) - (S * INV_TAU) / np;
  #pragma unroll
  for (int off = 32; off > 0; off >>= 1) v += __shfl_xor(v, off);
  __shared__ float ws2[2];
  const int wave = threadIdx.x >> 6, lane = threadIdx.x & 63;
  if (lane == 0) ws2[wave] = v;
  __syncthreads();
  if (threadIdx.x == 0) atomicAdd(out, (ws2[0] + ws2[1]) * (1.0f / (float)N_ROWS));
}

extern "C" void kernel_launch(void* const* d_in, const int* in_sizes, int n_in,
                              void* d_out, int out_size, void* d_ws, size_t ws_size,
                              hipStream_t stream) {
  const float* z1 = (const float*)d_in[0];
  const float* z2 = (const float*)d_in[1];
  const int* labels = (const int*)d_in[2];
  float* out = (float*)d_out;
  char* ws = (char*)d_ws;

  unsigned int* zbf    = (unsigned int*)(ws);
  uint2* labs8         = (uint2*)(ws + 2097152);
  int* s               = (int*)(ws + 4194304);
  float* part          = (float*)(ws + 4210688);

  hipLaunchKernelGGL(k_norm_pack, dim3(2048), dim3(256), 0, stream,
                     z1, z2, labels, zbf, labs8, s, part, out);
  hipLaunchKernelGGL(k_fused, dim3(528), dim3(512), 0, stream,
                     (const unsigned char*)labs8, s, (const unsigned short*)zbf, part);
  hipLaunchKernelGGL(k_loss, dim3(32), dim3(128), 0, stream, part, out);
}